// Round 1
// baseline (3554.364 us; speedup 1.0000x reference)
//
#include <hip/hip_runtime.h>
#include <math.h>
#include <float.h>

#define B_   16
#define C1_  512
#define H1_  64
#define C2_  1024
#define H2_  32
#define CT_  1536   // C1 + C2
#define OUT_ 256
#define P_   2048

// ---------------- centroid squared norms -> ws ----------------
__global__ void cnorm_kernel(const float* __restrict__ cent, float* __restrict__ nc) {
    const int t = threadIdx.x;
    const int wave = t >> 6;
    const int lane = t & 63;
    const int p = blockIdx.x * 4 + wave;
    const float4 v = ((const float4*)(cent + (size_t)p * OUT_))[lane];
    float s = v.x * v.x + v.y * v.y + v.z * v.z + v.w * v.w;
#pragma unroll
    for (int m = 1; m < 64; m <<= 1) s += __shfl_xor(s, m);
    if (lane == 0) nc[p] = s;
}

// ---------------- fused pool/resize/project/distance/top3 ----------------
struct SMem {
    float e[OUT_][64];          // 64 KB  emb tile, c-major (persistent)
    float ne[64];               // ||e||^2 per pixel
    union {
        struct {
            float wlds[8][OUT_];        // 8 KB  proj_w K-tile, c-major
            float s[8][64];             // 2 KB  sample K-tile
            float pp[8][2][32];         // 2 KB  pooled p2 rows per channel group
        } ph1;
        float ct[8][OUT_];              // 8 KB  centroid K-tile, c-major
        float part[4][64];              // ne partials
    } u;
};

__global__ __launch_bounds__(256, 2)
void fused_kernel(const float* __restrict__ p1, const float* __restrict__ p2,
                  const float* __restrict__ projw, const float* __restrict__ projb,
                  const float* __restrict__ cent, const float* __restrict__ ncg,
                  float* __restrict__ outp) {
    __shared__ SMem sm;
    const int t = threadIdx.x;
    const int b = blockIdx.x >> 6;
    const int h = blockIdx.x & 63;

    // bilinear row taps for this output row (half-pixel, clamped == JAX renorm)
    const float fh = h * 0.5f - 0.25f;
    const int jh = (int)floorf(fh);
    const float th = fh - (float)jh;
    const int jh0 = max(jh, 0);
    const int jh1 = min(jh + 1, H2_ - 1);

    const int og = t >> 3, wg = t & 7;      // GEMM tile: 8 o x 8 w per thread
    const int cl = t >> 5, l32 = t & 31;    // staging: 8 channels x 32 lanes
    const int w0 = l32 * 2;
    const float inv9 = 1.f / 9.f;

    float acc[8][8];
#pragma unroll
    for (int i = 0; i < 8; ++i)
#pragma unroll
        for (int j = 0; j < 8; ++j) acc[i][j] = 0.f;

    // ================= Phase 1: projection GEMM, K = 1536 in tiles of 8 =================
    for (int kt = 0; kt < CT_ / 8; ++kt) {
        const int c0 = kt * 8;

        // --- global loads issued before barrier (overlap with prev GEMM) ---
        const float* wr = projw + (size_t)t * CT_ + c0;
        const float4 wv0 = *(const float4*)wr;
        const float4 wv1 = *(const float4*)(wr + 4);

        float sv0 = 0.f, sv1 = 0.f;       // p1 path: two sample values
        float pa0 = 0.f, pa1 = 0.f;       // p2 path: two pooled values
        int rsel = 0, cp = 0;
        if (c0 < C1_) {
            const int c = c0 + cl;
            const float* pb = p1 + ((size_t)(b * C1_ + c)) * (H1_ * H1_);
            float cs0 = 0.f, cs1 = 0.f, cs2 = 0.f, cs3 = 0.f;
#pragma unroll
            for (int r = -1; r <= 1; ++r) {
                const int hh = h + r;
                if (hh >= 0 && hh < H1_) {
                    const float* row = pb + hh * H1_;
                    if (w0 - 1 >= 0)  cs0 += row[w0 - 1];
                    cs1 += row[w0];
                    cs2 += row[w0 + 1];
                    if (w0 + 2 < H1_) cs3 += row[w0 + 2];
                }
            }
            sv0 = (cs0 + cs1 + cs2) * inv9;
            sv1 = (cs1 + cs2 + cs3) * inv9;
        } else {
            const int c2 = c0 + cl - C1_;
            rsel = l32 >> 4;
            cp = (l32 & 15) * 2;
            const int jr = rsel ? jh1 : jh0;
            const float* pb = p2 + ((size_t)(b * C2_ + c2)) * (H2_ * H2_);
            float cs0 = 0.f, cs1 = 0.f, cs2 = 0.f, cs3 = 0.f;
#pragma unroll
            for (int r = -1; r <= 1; ++r) {
                const int hh = jr + r;
                if (hh >= 0 && hh < H2_) {
                    const float* row = pb + hh * H2_;
                    if (cp - 1 >= 0)  cs0 += row[cp - 1];
                    cs1 += row[cp];
                    cs2 += row[cp + 1];
                    if (cp + 2 < H2_) cs3 += row[cp + 2];
                }
            }
            pa0 = (cs0 + cs1 + cs2) * inv9;
            pa1 = (cs1 + cs2 + cs3) * inv9;
        }

        __syncthreads();   // (1) previous GEMM done reading LDS

        sm.u.ph1.wlds[0][t] = wv0.x; sm.u.ph1.wlds[1][t] = wv0.y;
        sm.u.ph1.wlds[2][t] = wv0.z; sm.u.ph1.wlds[3][t] = wv0.w;
        sm.u.ph1.wlds[4][t] = wv1.x; sm.u.ph1.wlds[5][t] = wv1.y;
        sm.u.ph1.wlds[6][t] = wv1.z; sm.u.ph1.wlds[7][t] = wv1.w;
        if (c0 < C1_) {
            sm.u.ph1.s[cl][w0]     = sv0;
            sm.u.ph1.s[cl][w0 + 1] = sv1;
        } else {
            sm.u.ph1.pp[cl][rsel][cp]     = pa0;
            sm.u.ph1.pp[cl][rsel][cp + 1] = pa1;
        }

        __syncthreads();   // (2) staged data visible

        if (c0 >= C1_) {   // bilinear interp to 64 wide (uniform branch)
#pragma unroll
            for (int q = 0; q < 2; ++q) {
                const int w = w0 + q;
                const float fw = w * 0.5f - 0.25f;
                const int jw = (int)floorf(fw);
                const float tw = fw - (float)jw;
                const int j0 = max(jw, 0);
                const int j1 = min(jw + 1, H2_ - 1);
                const float v0 = (1.f - tw) * sm.u.ph1.pp[cl][0][j0] + tw * sm.u.ph1.pp[cl][0][j1];
                const float v1 = (1.f - tw) * sm.u.ph1.pp[cl][1][j0] + tw * sm.u.ph1.pp[cl][1][j1];
                sm.u.ph1.s[cl][w] = (1.f - th) * v0 + th * v1;
            }
            __syncthreads();   // (3) s ready
        }

        // --- register-blocked rank-8 update ---
#pragma unroll
        for (int k = 0; k < 8; ++k) {
            const float4 a0 = *(const float4*)&sm.u.ph1.wlds[k][og * 8];
            const float4 a1 = *(const float4*)&sm.u.ph1.wlds[k][og * 8 + 4];
            const float4 b0 = *(const float4*)&sm.u.ph1.s[k][wg * 8];
            const float4 b1 = *(const float4*)&sm.u.ph1.s[k][wg * 8 + 4];
            const float av[8] = {a0.x, a0.y, a0.z, a0.w, a1.x, a1.y, a1.z, a1.w};
            const float bv[8] = {b0.x, b0.y, b0.z, b0.w, b1.x, b1.y, b1.z, b1.w};
#pragma unroll
            for (int i = 0; i < 8; ++i)
#pragma unroll
                for (int j = 0; j < 8; ++j)
                    acc[i][j] = fmaf(av[i], bv[j], acc[i][j]);
        }
        __syncthreads();   // (4) done reading before next stage overwrites
    }

    // ---- bias + write emb to LDS ----
    const float4 bb0 = *(const float4*)&projb[og * 8];
    const float4 bb1 = *(const float4*)&projb[og * 8 + 4];
    const float bv8[8] = {bb0.x, bb0.y, bb0.z, bb0.w, bb1.x, bb1.y, bb1.z, bb1.w};
#pragma unroll
    for (int i = 0; i < 8; ++i) {
        const float4 o0 = make_float4(acc[i][0] + bv8[i], acc[i][1] + bv8[i],
                                      acc[i][2] + bv8[i], acc[i][3] + bv8[i]);
        const float4 o1 = make_float4(acc[i][4] + bv8[i], acc[i][5] + bv8[i],
                                      acc[i][6] + bv8[i], acc[i][7] + bv8[i]);
        *(float4*)&sm.e[og * 8 + i][wg * 8]     = o0;
        *(float4*)&sm.e[og * 8 + i][wg * 8 + 4] = o1;
    }
    __syncthreads();

    // ---- ||e||^2 per pixel ----
    {
        const int px = t & 63, prt = t >> 6;
        float s2 = 0.f;
#pragma unroll 8
        for (int o = 0; o < 64; ++o) {
            const float v = sm.e[prt * 64 + o][px];
            s2 = fmaf(v, v, s2);
        }
        sm.u.part[prt][px] = s2;
        __syncthreads();
        if (t < 64)
            sm.ne[t] = sm.u.part[0][t] + sm.u.part[1][t] + sm.u.part[2][t] + sm.u.part[3][t];
        // next barrier (inside phase 2) publishes ne before any ct overwrite
    }

    // ================= Phase 2: distance GEMM + fused top-3 =================
    const int pxg = t >> 5;   // 8 groups of 8 pixels
    const int pg  = t & 31;   // 32 groups of 8 centroids
    float t3a[8], t3b[8], t3c[8];
#pragma unroll
    for (int i = 0; i < 8; ++i) { t3a[i] = FLT_MAX; t3b[i] = FLT_MAX; t3c[i] = FLT_MAX; }

    for (int pt = 0; pt < 8; ++pt) {
        const int p0 = pt * 256;
        float a2[8][8];
#pragma unroll
        for (int i = 0; i < 8; ++i)
#pragma unroll
            for (int j = 0; j < 8; ++j) a2[i][j] = 0.f;

        for (int kt2 = 0; kt2 < OUT_ / 8; ++kt2) {
            const int c0 = kt2 * 8;
            const float* cr = cent + (size_t)(p0 + t) * OUT_ + c0;
            const float4 cv0 = *(const float4*)cr;
            const float4 cv1 = *(const float4*)(cr + 4);
            __syncthreads();   // prev GEMM done reading ct (also guards ne/part)
            sm.u.ct[0][t] = cv0.x; sm.u.ct[1][t] = cv0.y; sm.u.ct[2][t] = cv0.z; sm.u.ct[3][t] = cv0.w;
            sm.u.ct[4][t] = cv1.x; sm.u.ct[5][t] = cv1.y; sm.u.ct[6][t] = cv1.z; sm.u.ct[7][t] = cv1.w;
            __syncthreads();
#pragma unroll
            for (int k = 0; k < 8; ++k) {
                const float4 a0 = *(const float4*)&sm.e[c0 + k][pxg * 8];
                const float4 a1 = *(const float4*)&sm.e[c0 + k][pxg * 8 + 4];
                const float4 b0 = *(const float4*)&sm.u.ct[k][pg * 8];
                const float4 b1 = *(const float4*)&sm.u.ct[k][pg * 8 + 4];
                const float av[8] = {a0.x, a0.y, a0.z, a0.w, a1.x, a1.y, a1.z, a1.w};
                const float bv[8] = {b0.x, b0.y, b0.z, b0.w, b1.x, b1.y, b1.z, b1.w};
#pragma unroll
                for (int i = 0; i < 8; ++i)
#pragma unroll
                    for (int j = 0; j < 8; ++j)
                        a2[i][j] = fmaf(av[i], bv[j], a2[i][j]);
            }
        }

        // top-3 of (||c||^2 - 2 e.c); ||e||^2 added at the end (constant per px)
        const float4 n0 = *(const float4*)&ncg[p0 + pg * 8];
        const float4 n1 = *(const float4*)&ncg[p0 + pg * 8 + 4];
        const float nv[8] = {n0.x, n0.y, n0.z, n0.w, n1.x, n1.y, n1.z, n1.w};
#pragma unroll
        for (int i = 0; i < 8; ++i)
#pragma unroll
            for (int j = 0; j < 8; ++j) {
                const float v  = fmaf(-2.f, a2[i][j], nv[j]);
                const float m0 = fminf(t3a[i], v);
                const float x0 = fmaxf(t3a[i], v);
                const float m1 = fminf(t3b[i], x0);
                const float x1 = fmaxf(t3b[i], x0);
                const float m2 = fminf(t3c[i], x1);
                t3a[i] = m0; t3b[i] = m1; t3c[i] = m2;
            }
    }

    // ---- merge top-3 across the 32 threads sharing each pixel group (half-wave) ----
#pragma unroll
    for (int m = 1; m < 32; m <<= 1) {
#pragma unroll
        for (int i = 0; i < 8; ++i) {
            const float b0 = __shfl_xor(t3a[i], m);
            const float b1 = __shfl_xor(t3b[i], m);
            const float b2 = __shfl_xor(t3c[i], m);
            const float c0m = fminf(t3a[i], b0);
            const float c1m = fminf(fmaxf(t3a[i], b0), fminf(t3b[i], b1));
            const float c2m = fminf(fminf(fmaxf(t3a[i], b1), fmaxf(t3b[i], b0)),
                                    fminf(t3c[i], b2));
            t3a[i] = c0m; t3b[i] = c1m; t3c[i] = c2m;
        }
    }

    // ---- softmin score, write out ----
    if (pg == 0) {
        float* orow = outp + ((size_t)b * (H1_ * H1_)) + h * H1_ + pxg * 8;
#pragma unroll
        for (int i = 0; i < 8; ++i) {
            const float nep = sm.ne[pxg * 8 + i];
            const float d0 = sqrtf(fmaxf(nep + t3a[i], 0.f));
            const float d1 = sqrtf(fmaxf(nep + t3b[i], 0.f));
            const float d2 = sqrtf(fmaxf(nep + t3c[i], 0.f));
            const float wsum = 1.f + expf(d0 - d1) + expf(d0 - d2);
            orow[i] = d0 / wsum;
        }
    }
}

extern "C" void kernel_launch(void* const* d_in, const int* in_sizes, int n_in,
                              void* d_out, int out_size, void* d_ws, size_t ws_size,
                              hipStream_t stream) {
    (void)in_sizes; (void)n_in; (void)out_size; (void)ws_size;
    const float* p1    = (const float*)d_in[0];
    const float* p2    = (const float*)d_in[1];
    const float* projw = (const float*)d_in[2];
    const float* projb = (const float*)d_in[3];
    const float* cent  = (const float*)d_in[4];
    float* outp = (float*)d_out;
    float* ncg  = (float*)d_ws;   // 2048 floats

    hipLaunchKernelGGL(cnorm_kernel, dim3(P_ / 4), dim3(256), 0, stream, cent, ncg);
    hipLaunchKernelGGL(fused_kernel, dim3(B_ * H1_), dim3(256), 0, stream,
                       p1, p2, projw, projb, cent, ncg, outp);
}

// Round 2
// 2689.389 us; speedup vs baseline: 1.3216x; 1.3216x over previous
//
#include <hip/hip_runtime.h>
#include <math.h>
#include <float.h>

#define B_   16
#define C1_  512
#define H1_  64
#define C2_  1024
#define H2_  32
#define CT_  1536   // C1 + C2
#define OUT_ 256
#define P_   2048

// ---------------- centroid squared norms -> ws ----------------
__global__ void cnorm_kernel(const float* __restrict__ cent, float* __restrict__ nc) {
    const int t = threadIdx.x;
    const int wave = t >> 6;
    const int lane = t & 63;
    const int p = blockIdx.x * 4 + wave;
    const float4 v = ((const float4*)(cent + (size_t)p * OUT_))[lane];
    float s = v.x * v.x + v.y * v.y + v.z * v.z + v.w * v.w;
#pragma unroll
    for (int m = 1; m < 64; m <<= 1) s += __shfl_xor(s, m);
    if (lane == 0) nc[p] = s;
}

// ---------------- fused pool/resize/project/distance/top3 ----------------
struct SMem {
    float e[OUT_][64];          // 64 KB  emb tile, c-major (persistent)
    float ne[64];               // ||e||^2 per pixel
    union {
        struct {
            float wlds[8][OUT_];        // 8 KB  proj_w K-tile, c-major
            float s[8][64];             // 2 KB  sample K-tile
            float pp[8][2][32];         // 2 KB  pooled p2 rows per channel group
        } ph1;
        float ct[8][OUT_];              // 8 KB  centroid K-tile, c-major
        float part[4][64];              // ne partials
    } u;
};

// Fragment mapping (bank-conflict-free): each thread owns TWO float4 chunks
// per operand: {idx*4 .. idx*4+3} and {HALF + idx*4 .. +3}. Within a wave the
// strided operand's ds_read_b128 is then 16B-lane-stride contiguous -> 0 conflicts.
// (Old mapping was one chunk of 8 at 32B stride -> 8-way conflict, 1.05e9 cycles.)

__global__ __launch_bounds__(256, 2)
void fused_kernel(const float* __restrict__ p1, const float* __restrict__ p2,
                  const float* __restrict__ projw, const float* __restrict__ projb,
                  const float* __restrict__ cent, const float* __restrict__ ncg,
                  float* __restrict__ outp) {
    __shared__ SMem sm;
    const int t = threadIdx.x;
    const int b = blockIdx.x >> 6;
    const int h = blockIdx.x & 63;

    // bilinear row taps for this output row (half-pixel, clamped == JAX renorm)
    const float fh = h * 0.5f - 0.25f;
    const int jh = (int)floorf(fh);
    const float th = fh - (float)jh;
    const int jh0 = max(jh, 0);
    const int jh1 = min(jh + 1, H2_ - 1);

    const int og = t >> 3, wg = t & 7;      // GEMM tile: 8 o x 8 w per thread
    const int cl = t >> 5, l32 = t & 31;    // staging: 8 channels x 32 lanes
    const int w0 = l32 * 2;
    const float inv9 = 1.f / 9.f;

    float acc[8][8];
#pragma unroll
    for (int i = 0; i < 8; ++i)
#pragma unroll
        for (int j = 0; j < 8; ++j) acc[i][j] = 0.f;

    // ================= Phase 1: projection GEMM, K = 1536 in tiles of 8 =================
    // thread output channels: o = og*4+i (i<4), 128+og*4+(i-4) (i>=4)
    // thread pixels:          w = wg*4+j (j<4), 32+wg*4+(j-4)  (j>=4)
    for (int kt = 0; kt < CT_ / 8; ++kt) {
        const int c0 = kt * 8;

        // --- global loads issued before barrier (overlap with prev GEMM) ---
        const float* wr = projw + (size_t)t * CT_ + c0;
        const float4 wv0 = *(const float4*)wr;
        const float4 wv1 = *(const float4*)(wr + 4);

        float sv0 = 0.f, sv1 = 0.f;       // p1 path: two sample values
        float pa0 = 0.f, pa1 = 0.f;       // p2 path: two pooled values
        int rsel = 0, cp = 0;
        if (c0 < C1_) {
            const int c = c0 + cl;
            const float* pb = p1 + ((size_t)(b * C1_ + c)) * (H1_ * H1_);
            float cs0 = 0.f, cs1 = 0.f, cs2 = 0.f, cs3 = 0.f;
#pragma unroll
            for (int r = -1; r <= 1; ++r) {
                const int hh = h + r;
                if (hh >= 0 && hh < H1_) {
                    const float* row = pb + hh * H1_;
                    if (w0 - 1 >= 0)  cs0 += row[w0 - 1];
                    cs1 += row[w0];
                    cs2 += row[w0 + 1];
                    if (w0 + 2 < H1_) cs3 += row[w0 + 2];
                }
            }
            sv0 = (cs0 + cs1 + cs2) * inv9;
            sv1 = (cs1 + cs2 + cs3) * inv9;
        } else {
            const int c2 = c0 + cl - C1_;
            rsel = l32 >> 4;
            cp = (l32 & 15) * 2;
            const int jr = rsel ? jh1 : jh0;
            const float* pb = p2 + ((size_t)(b * C2_ + c2)) * (H2_ * H2_);
            float cs0 = 0.f, cs1 = 0.f, cs2 = 0.f, cs3 = 0.f;
#pragma unroll
            for (int r = -1; r <= 1; ++r) {
                const int hh = jr + r;
                if (hh >= 0 && hh < H2_) {
                    const float* row = pb + hh * H2_;
                    if (cp - 1 >= 0)  cs0 += row[cp - 1];
                    cs1 += row[cp];
                    cs2 += row[cp + 1];
                    if (cp + 2 < H2_) cs3 += row[cp + 2];
                }
            }
            pa0 = (cs0 + cs1 + cs2) * inv9;
            pa1 = (cs1 + cs2 + cs3) * inv9;
        }

        __syncthreads();   // (1) previous GEMM done reading LDS

        sm.u.ph1.wlds[0][t] = wv0.x; sm.u.ph1.wlds[1][t] = wv0.y;
        sm.u.ph1.wlds[2][t] = wv0.z; sm.u.ph1.wlds[3][t] = wv0.w;
        sm.u.ph1.wlds[4][t] = wv1.x; sm.u.ph1.wlds[5][t] = wv1.y;
        sm.u.ph1.wlds[6][t] = wv1.z; sm.u.ph1.wlds[7][t] = wv1.w;
        if (c0 < C1_) {
            sm.u.ph1.s[cl][w0]     = sv0;
            sm.u.ph1.s[cl][w0 + 1] = sv1;
        } else {
            sm.u.ph1.pp[cl][rsel][cp]     = pa0;
            sm.u.ph1.pp[cl][rsel][cp + 1] = pa1;
        }

        __syncthreads();   // (2) staged data visible

        if (c0 >= C1_) {   // bilinear interp to 64 wide (uniform branch)
#pragma unroll
            for (int q = 0; q < 2; ++q) {
                const int w = w0 + q;
                const float fw = w * 0.5f - 0.25f;
                const int jw = (int)floorf(fw);
                const float tw = fw - (float)jw;
                const int j0 = max(jw, 0);
                const int j1 = min(jw + 1, H2_ - 1);
                const float v0 = (1.f - tw) * sm.u.ph1.pp[cl][0][j0] + tw * sm.u.ph1.pp[cl][0][j1];
                const float v1 = (1.f - tw) * sm.u.ph1.pp[cl][1][j0] + tw * sm.u.ph1.pp[cl][1][j1];
                sm.u.ph1.s[cl][w] = (1.f - th) * v0 + th * v1;
            }
            __syncthreads();   // (3) s ready
        }

        // --- register-blocked rank-8 update (split-chunk, conflict-free) ---
#pragma unroll
        for (int k = 0; k < 8; ++k) {
            const float4 a0 = *(const float4*)&sm.u.ph1.wlds[k][og * 4];
            const float4 a1 = *(const float4*)&sm.u.ph1.wlds[k][128 + og * 4];
            const float4 b0 = *(const float4*)&sm.u.ph1.s[k][wg * 4];
            const float4 b1 = *(const float4*)&sm.u.ph1.s[k][32 + wg * 4];
            const float av[8] = {a0.x, a0.y, a0.z, a0.w, a1.x, a1.y, a1.z, a1.w};
            const float bv[8] = {b0.x, b0.y, b0.z, b0.w, b1.x, b1.y, b1.z, b1.w};
#pragma unroll
            for (int i = 0; i < 8; ++i)
#pragma unroll
                for (int j = 0; j < 8; ++j)
                    acc[i][j] = fmaf(av[i], bv[j], acc[i][j]);
        }
        __syncthreads();   // (4) done reading before next stage overwrites
    }

    // ---- bias + write emb to LDS (split-chunk rows) ----
    const float4 bb0 = *(const float4*)&projb[og * 4];
    const float4 bb1 = *(const float4*)&projb[128 + og * 4];
    const float bv8[8] = {bb0.x, bb0.y, bb0.z, bb0.w, bb1.x, bb1.y, bb1.z, bb1.w};
#pragma unroll
    for (int i = 0; i < 8; ++i) {
        const int row = (i < 4) ? (og * 4 + i) : (128 + og * 4 + (i - 4));
        const float4 lo = make_float4(acc[i][0] + bv8[i], acc[i][1] + bv8[i],
                                      acc[i][2] + bv8[i], acc[i][3] + bv8[i]);
        const float4 hi = make_float4(acc[i][4] + bv8[i], acc[i][5] + bv8[i],
                                      acc[i][6] + bv8[i], acc[i][7] + bv8[i]);
        *(float4*)&sm.e[row][wg * 4]      = lo;
        *(float4*)&sm.e[row][32 + wg * 4] = hi;
    }
    __syncthreads();

    // ---- ||e||^2 per pixel ----
    {
        const int px = t & 63, prt = t >> 6;
        float s2 = 0.f;
#pragma unroll 8
        for (int o = 0; o < 64; ++o) {
            const float v = sm.e[prt * 64 + o][px];
            s2 = fmaf(v, v, s2);
        }
        sm.u.part[prt][px] = s2;
        __syncthreads();
        if (t < 64)
            sm.ne[t] = sm.u.part[0][t] + sm.u.part[1][t] + sm.u.part[2][t] + sm.u.part[3][t];
        // next barrier (inside phase 2) publishes ne before any ct overwrite
    }

    // ================= Phase 2: distance GEMM + fused top-3 =================
    // thread pixels:    pxg*8 .. pxg*8+7 (broadcast across 32 lanes)
    // thread centroids: p0 + pg*4 + j (j<4), p0 + 128 + pg*4 + (j-4) (j>=4)
    const int pxg = t >> 5;   // 8 groups of 8 pixels
    const int pg  = t & 31;   // 32 threads share a pixel group
    float t3a[8], t3b[8], t3c[8];
#pragma unroll
    for (int i = 0; i < 8; ++i) { t3a[i] = FLT_MAX; t3b[i] = FLT_MAX; t3c[i] = FLT_MAX; }

    for (int pt = 0; pt < 8; ++pt) {
        const int p0 = pt * 256;
        float a2[8][8];
#pragma unroll
        for (int i = 0; i < 8; ++i)
#pragma unroll
            for (int j = 0; j < 8; ++j) a2[i][j] = 0.f;

        for (int kt2 = 0; kt2 < OUT_ / 8; ++kt2) {
            const int c0 = kt2 * 8;
            const float* cr = cent + (size_t)(p0 + t) * OUT_ + c0;
            const float4 cv0 = *(const float4*)cr;
            const float4 cv1 = *(const float4*)(cr + 4);
            __syncthreads();   // prev GEMM done reading ct (also guards ne/part)
            sm.u.ct[0][t] = cv0.x; sm.u.ct[1][t] = cv0.y; sm.u.ct[2][t] = cv0.z; sm.u.ct[3][t] = cv0.w;
            sm.u.ct[4][t] = cv1.x; sm.u.ct[5][t] = cv1.y; sm.u.ct[6][t] = cv1.z; sm.u.ct[7][t] = cv1.w;
            __syncthreads();
#pragma unroll
            for (int k = 0; k < 8; ++k) {
                const float4 a0 = *(const float4*)&sm.e[c0 + k][pxg * 8];
                const float4 a1 = *(const float4*)&sm.e[c0 + k][pxg * 8 + 4];
                const float4 b0 = *(const float4*)&sm.u.ct[k][pg * 4];
                const float4 b1 = *(const float4*)&sm.u.ct[k][128 + pg * 4];
                const float av[8] = {a0.x, a0.y, a0.z, a0.w, a1.x, a1.y, a1.z, a1.w};
                const float bv[8] = {b0.x, b0.y, b0.z, b0.w, b1.x, b1.y, b1.z, b1.w};
#pragma unroll
                for (int i = 0; i < 8; ++i)
#pragma unroll
                    for (int j = 0; j < 8; ++j)
                        a2[i][j] = fmaf(av[i], bv[j], a2[i][j]);
            }
        }

        // top-3 of (||c||^2 - 2 e.c); ||e||^2 added at the end (constant per px)
        const float4 n0 = *(const float4*)&ncg[p0 + pg * 4];
        const float4 n1 = *(const float4*)&ncg[p0 + 128 + pg * 4];
        const float nv[8] = {n0.x, n0.y, n0.z, n0.w, n1.x, n1.y, n1.z, n1.w};
#pragma unroll
        for (int i = 0; i < 8; ++i)
#pragma unroll
            for (int j = 0; j < 8; ++j) {
                const float v  = fmaf(-2.f, a2[i][j], nv[j]);
                const float m0 = fminf(t3a[i], v);
                const float x0 = fmaxf(t3a[i], v);
                const float m1 = fminf(t3b[i], x0);
                const float x1 = fmaxf(t3b[i], x0);
                const float m2 = fminf(t3c[i], x1);
                t3a[i] = m0; t3b[i] = m1; t3c[i] = m2;
            }
    }

    // ---- merge top-3 across the 32 threads sharing each pixel group (half-wave) ----
#pragma unroll
    for (int m = 1; m < 32; m <<= 1) {
#pragma unroll
        for (int i = 0; i < 8; ++i) {
            const float b0 = __shfl_xor(t3a[i], m);
            const float b1 = __shfl_xor(t3b[i], m);
            const float b2 = __shfl_xor(t3c[i], m);
            const float c0m = fminf(t3a[i], b0);
            const float c1m = fminf(fmaxf(t3a[i], b0), fminf(t3b[i], b1));
            const float c2m = fminf(fminf(fmaxf(t3a[i], b1), fmaxf(t3b[i], b0)),
                                    fminf(t3c[i], b2));
            t3a[i] = c0m; t3b[i] = c1m; t3c[i] = c2m;
        }
    }

    // ---- softmin score, write out ----
    if (pg == 0) {
        float* orow = outp + ((size_t)b * (H1_ * H1_)) + h * H1_ + pxg * 8;
#pragma unroll
        for (int i = 0; i < 8; ++i) {
            const float nep = sm.ne[pxg * 8 + i];
            const float d0 = sqrtf(fmaxf(nep + t3a[i], 0.f));
            const float d1 = sqrtf(fmaxf(nep + t3b[i], 0.f));
            const float d2 = sqrtf(fmaxf(nep + t3c[i], 0.f));
            const float wsum = 1.f + expf(d0 - d1) + expf(d0 - d2);
            orow[i] = d0 / wsum;
        }
    }
}

extern "C" void kernel_launch(void* const* d_in, const int* in_sizes, int n_in,
                              void* d_out, int out_size, void* d_ws, size_t ws_size,
                              hipStream_t stream) {
    (void)in_sizes; (void)n_in; (void)out_size; (void)ws_size;
    const float* p1    = (const float*)d_in[0];
    const float* p2    = (const float*)d_in[1];
    const float* projw = (const float*)d_in[2];
    const float* projb = (const float*)d_in[3];
    const float* cent  = (const float*)d_in[4];
    float* outp = (float*)d_out;
    float* ncg  = (float*)d_ws;   // 2048 floats

    hipLaunchKernelGGL(cnorm_kernel, dim3(P_ / 4), dim3(256), 0, stream, cent, ncg);
    hipLaunchKernelGGL(fused_kernel, dim3(B_ * H1_), dim3(256), 0, stream,
                       p1, p2, projw, projb, cent, ncg, outp);
}

// Round 3
// 909.506 us; speedup vs baseline: 3.9080x; 2.9570x over previous
//
#include <hip/hip_runtime.h>
#include <math.h>
#include <float.h>

#define B_   16
#define C1_  512
#define H1_  64
#define C2_  1024
#define H2_  32
#define CT_  1536   // C1 + C2
#define OUT_ 256
#define P_   2048

// ---- workspace layout (bytes). REQUIRES ws_size >= 3678208 (~3.51 MB) ----
#define WS_NCG   0            // 2048 f32          (8192 B)
#define WS_WHI   8192         // proj_w frag image hi: 48*16 frags *64 lanes *16B = 786432
#define WS_WLO   794624       // lo plane, same size
#define WS_CHI   1581056      // cent frag image hi: 16*8*8 frags *64 *16B = 1048576
#define WS_CLO   2629632      // lo plane
#define WS_TOT   3678208

// ---- LDS layout (bytes) ----
#define LDS_EHI  0            // emb hi  [64 px][264 ushort] rows (528B stride, 256 used)
#define LDS_ELO  33792
#define LDS_SHI  67584        // sample hi [64 px][72 ushort] rows (144B stride, 64 ch used)
#define LDS_SLO  76800
#define LDS_SS   86016        // f32 [64][68]  (pool staging / pp / wmerge union) 17408 B
#define LDS_WM   86016        // union with SS: [8 waves][64 px][4 f32] = 8192 B
#define LDS_NE   103424       // 64 f32
#define LDS_TOT  103680

typedef __attribute__((ext_vector_type(8))) short sh8;
typedef __attribute__((ext_vector_type(4))) float f32x4;
#define MFMA(a,b,c) __builtin_amdgcn_mfma_f32_16x16x32_bf16(a, b, c, 0, 0, 0)

__device__ __forceinline__ unsigned short bf_hi(float x) {
    union { float f; unsigned u; } a; a.f = x;
    unsigned r = a.u + 0x7FFFu + ((a.u >> 16) & 1u);
    return (unsigned short)(r >> 16);
}
__device__ __forceinline__ float bf_f(unsigned short h) {
    union { unsigned u; float f; } a; a.u = ((unsigned)h) << 16;
    return a.f;
}
__device__ __forceinline__ void bsplit(float x, unsigned short& hi, unsigned short& lo) {
    hi = bf_hi(x);
    lo = bf_hi(x - bf_f(hi));
}

// ---------------- centroid squared norms -> ws ----------------
__global__ void cnorm_kernel(const float* __restrict__ cent, float* __restrict__ nc) {
    const int t = threadIdx.x;
    const int wave = t >> 6, lane = t & 63;
    const int p = blockIdx.x * 4 + wave;
    const float4 v = ((const float4*)(cent + (size_t)p * OUT_))[lane];
    float s = v.x * v.x + v.y * v.y + v.z * v.z + v.w * v.w;
#pragma unroll
    for (int m = 1; m < 64; m <<= 1) s += __shfl_xor(s, m);
    if (lane == 0) nc[p] = s;
}

// ---------------- bake proj_w into lane-ordered frag images ----------------
// frag = step(0..47)*16 + mtile(0..15); lane l: out = mtile*16+(l&15),
// k = step*32 + (l>>4)*8 + e (e=0..7). Image: (frag*64 + l)*8 ushorts.
__global__ void prep_w(const float* __restrict__ projw,
                       unsigned short* __restrict__ whi, unsigned short* __restrict__ wlo) {
    const int fid = blockIdx.x * 256 + threadIdx.x;   // 49152 total
    const int frag = fid >> 6, l = fid & 63;
    const int step = frag >> 4, mt = frag & 15;
    const int out = mt * 16 + (l & 15);
    const int ch = step * 32 + (l >> 4) * 8;
    const float* src = projw + (size_t)out * CT_ + ch;
    const float4 a = *(const float4*)src;
    const float4 b = *(const float4*)(src + 4);
    const float v[8] = {a.x, a.y, a.z, a.w, b.x, b.y, b.z, b.w};
    unsigned short* dh = whi + (size_t)fid * 8;
    unsigned short* dl = wlo + (size_t)fid * 8;
#pragma unroll
    for (int e = 0; e < 8; ++e) { unsigned short h, lo2; bsplit(v[e], h, lo2); dh[e] = h; dl[e] = lo2; }
}

// ---------------- bake centroids into lane-ordered frag images ----------------
// frag = (chunk(0..15)*8 + tile(0..7))*8 + ks(0..7); lane l: c = chunk*128+tile*16+(l&15),
// k = ks*32 + (l>>4)*8 + e.
__global__ void prep_c(const float* __restrict__ cent,
                       unsigned short* __restrict__ chi, unsigned short* __restrict__ clo) {
    const int fid = blockIdx.x * 256 + threadIdx.x;   // 65536 total
    const int frag = fid >> 6, l = fid & 63;
    const int chunk = frag >> 6, tile = (frag >> 3) & 7, ks = frag & 7;
    const int c = chunk * 128 + tile * 16 + (l & 15);
    const int k = ks * 32 + (l >> 4) * 8;
    const float* src = cent + (size_t)c * OUT_ + k;
    const float4 a = *(const float4*)src;
    const float4 b = *(const float4*)(src + 4);
    const float v[8] = {a.x, a.y, a.z, a.w, b.x, b.y, b.z, b.w};
    unsigned short* dh = chi + (size_t)fid * 8;
    unsigned short* dl = clo + (size_t)fid * 8;
#pragma unroll
    for (int e = 0; e < 8; ++e) { unsigned short h, lo2; bsplit(v[e], h, lo2); dh[e] = h; dl[e] = lo2; }
}

// ---------------- fused: pool/resize -> proj (MFMA) -> dist (MFMA) -> top3 ----------------
__global__ __launch_bounds__(512, 2)
void fused2(const float* __restrict__ p1, const float* __restrict__ p2,
            const float* __restrict__ projb,
            const unsigned short* __restrict__ whi, const unsigned short* __restrict__ wlo,
            const unsigned short* __restrict__ chi, const unsigned short* __restrict__ clo,
            const float* __restrict__ ncg, float* __restrict__ outp) {
    __shared__ __align__(16) char sm[LDS_TOT];
    unsigned short* eh  = (unsigned short*)(sm + LDS_EHI);
    unsigned short* el  = (unsigned short*)(sm + LDS_ELO);
    unsigned short* shp = (unsigned short*)(sm + LDS_SHI);
    unsigned short* slp = (unsigned short*)(sm + LDS_SLO);
    float* SSf = (float*)(sm + LDS_SS);
    float* neL = (float*)(sm + LDS_NE);

    const int t = threadIdx.x;
    const int b = blockIdx.x >> 6, h = blockIdx.x & 63;
    const int l = t & 63, li = l & 15, g = l >> 4, w8 = t >> 6;
    const float inv9 = 1.f / 9.f;

    // bilinear row taps (half-pixel, clamped == JAX edge renorm)
    const float fh = h * 0.5f - 0.25f;
    const int jh = (int)floorf(fh);
    const float th = fh - (float)jh;
    const int jh0 = max(jh, 0), jh1 = min(jh + 1, H2_ - 1);

    // pooling ids
    const int cl = t >> 3, q8 = t & 7;
    const int px0 = q8 * 8;                        // p1 path
    const int rsel = q8 >> 2, w4 = (q8 & 3) * 8;   // p2 path
    const int jr = rsel ? jh1 : jh0;
    // transpose ids
    const int tpx = t >> 3, tq = t & 7;
    const float fw = tpx * 0.5f - 0.25f;
    const int jw = (int)floorf(fw);
    const float tw = fw - (float)jw;
    const int j0 = max(jw, 0), j1 = min(jw + 1, H2_ - 1);

    // ================= Phase 1: projection, 24 stages of 64 channels =================
    f32x4 acc1[2][4];
#pragma unroll
    for (int i = 0; i < 2; ++i)
#pragma unroll
        for (int j = 0; j < 4; ++j) acc1[i][j] = (f32x4)0.f;

    for (int st = 0; st < 24; ++st) {
        // ---- pool into SS (fp32) ----
        if (st < 8) {
            const int ch = st * 64 + cl;
            const float* pb = p1 + ((size_t)(b * C1_ + ch)) * (H1_ * H1_);
            float cs[10];
#pragma unroll
            for (int i = 0; i < 10; ++i) cs[i] = 0.f;
#pragma unroll
            for (int r = -1; r <= 1; ++r) {
                const int hh = h + r;
                if (hh >= 0 && hh < H1_) {
                    const float* row = pb + hh * H1_ + px0;
                    if (px0 > 0) cs[0] += row[-1];
                    const float4 a = *(const float4*)row;
                    const float4 bb = *(const float4*)(row + 4);
                    cs[1] += a.x; cs[2] += a.y; cs[3] += a.z; cs[4] += a.w;
                    cs[5] += bb.x; cs[6] += bb.y; cs[7] += bb.z; cs[8] += bb.w;
                    if (px0 < 56) cs[9] += row[8];
                }
            }
            float* dst = SSf + cl * 68 + px0;
            f32x4 v0 = {(cs[0]+cs[1]+cs[2])*inv9, (cs[1]+cs[2]+cs[3])*inv9,
                        (cs[2]+cs[3]+cs[4])*inv9, (cs[3]+cs[4]+cs[5])*inv9};
            f32x4 v1 = {(cs[4]+cs[5]+cs[6])*inv9, (cs[5]+cs[6]+cs[7])*inv9,
                        (cs[6]+cs[7]+cs[8])*inv9, (cs[7]+cs[8]+cs[9])*inv9};
            *(f32x4*)dst = v0; *(f32x4*)(dst + 4) = v1;
        } else {
            const int ch2 = (st - 8) * 64 + cl;
            const float* pb = p2 + ((size_t)(b * C2_ + ch2)) * (H2_ * H2_);
            float cs[10];
#pragma unroll
            for (int i = 0; i < 10; ++i) cs[i] = 0.f;
#pragma unroll
            for (int r = -1; r <= 1; ++r) {
                const int hh = jr + r;
                if (hh >= 0 && hh < H2_) {
                    const float* row = pb + hh * H2_ + w4;
                    if (w4 > 0) cs[0] += row[-1];
                    const float4 a = *(const float4*)row;
                    const float4 bb = *(const float4*)(row + 4);
                    cs[1] += a.x; cs[2] += a.y; cs[3] += a.z; cs[4] += a.w;
                    cs[5] += bb.x; cs[6] += bb.y; cs[7] += bb.z; cs[8] += bb.w;
                    if (w4 < 24) cs[9] += row[8];
                }
            }
            float* dst = SSf + cl * 68 + rsel * 36 + w4;
            f32x4 v0 = {(cs[0]+cs[1]+cs[2])*inv9, (cs[1]+cs[2]+cs[3])*inv9,
                        (cs[2]+cs[3]+cs[4])*inv9, (cs[3]+cs[4]+cs[5])*inv9};
            f32x4 v1 = {(cs[4]+cs[5]+cs[6])*inv9, (cs[5]+cs[6]+cs[7])*inv9,
                        (cs[6]+cs[7]+cs[8])*inv9, (cs[7]+cs[8]+cs[9])*inv9};
            *(f32x4*)dst = v0; *(f32x4*)(dst + 4) = v1;
        }
        __syncthreads();   // SS staged

        // ---- transpose (+interp for p2) -> bf16 hi/lo sample tile ----
        {
            float v[8];
            if (st < 8) {
#pragma unroll
                for (int e = 0; e < 8; ++e) v[e] = SSf[(tq + 8 * e) * 68 + tpx];
            } else {
#pragma unroll
                for (int e = 0; e < 8; ++e) {
                    const float* rp = SSf + (tq + 8 * e) * 68;
                    const float p00 = rp[j0], p01 = rp[j1];
                    const float p10 = rp[36 + j0], p11 = rp[36 + j1];
                    const float vw0 = p00 + tw * (p01 - p00);
                    const float vw1 = p10 + tw * (p11 - p10);
                    v[e] = vw0 + th * (vw1 - vw0);
                }
            }
#pragma unroll
            for (int e = 0; e < 8; ++e) {
                unsigned short hi, lo;
                bsplit(v[e], hi, lo);
                shp[tpx * 72 + e * 8 + tq] = hi;   // channel k = tq + 8e -> chunk e, pos tq
                slp[tpx * 72 + e * 8 + tq] = lo;
            }
        }
        __syncthreads();   // sample tile ready

        // ---- frag loop: 2 K-steps of 32 ----
#pragma unroll
        for (int ks2 = 0; ks2 < 2; ++ks2) {
            const int step = st * 2 + ks2;
            sh8 ah[2], al[2], bh[4], bl[4];
#pragma unroll
            for (int mt = 0; mt < 2; ++mt) {
                const size_t off = ((size_t)((step * 16 + (w8 * 2 + mt)) * 64 + l)) * 8;
                ah[mt] = *(const sh8*)(whi + off);
                al[mt] = *(const sh8*)(wlo + off);
            }
#pragma unroll
            for (int nt = 0; nt < 4; ++nt) {
                const int sb = (nt * 16 + li) * 72 + (ks2 * 4 + g) * 8;
                bh[nt] = *(const sh8*)(shp + sb);
                bl[nt] = *(const sh8*)(slp + sb);
            }
#pragma unroll
            for (int mt = 0; mt < 2; ++mt)
#pragma unroll
                for (int nt = 0; nt < 4; ++nt) {
                    f32x4 c = acc1[mt][nt];
                    c = MFMA(ah[mt], bh[nt], c);
                    c = MFMA(ah[mt], bl[nt], c);
                    c = MFMA(al[mt], bh[nt], c);
                    acc1[mt][nt] = c;
                }
        }
        // no barrier: next stage's SS write is ordered by the first barrier above
    }

    // ---- bias + split + store emb to LDS (layout: [px][out], chunk=out>>3, pos=out&7) ----
#pragma unroll
    for (int mt = 0; mt < 2; ++mt) {
        const f32x4 b4 = *(const f32x4*)(projb + w8 * 32 + mt * 16 + g * 4);
#pragma unroll
        for (int nt = 0; nt < 4; ++nt) {
            const int px = nt * 16 + li;
#pragma unroll
            for (int r = 0; r < 4; ++r) {
                const int out = w8 * 32 + mt * 16 + g * 4 + r;
                unsigned short hi, lo;
                bsplit(acc1[mt][nt][r] + b4[r], hi, lo);
                eh[px * 264 + out] = hi;   // (out>>3)*8 + (out&7) == out
                el[px * 264 + out] = lo;
            }
        }
    }
    __syncthreads();

    // ---- ||e||^2 per pixel (from the exact bf16 hi+lo values) ----
    {
        const int npx = t >> 3, oc = t & 7;
        float s2 = 0.f;
#pragma unroll
        for (int j = 0; j < 4; ++j) {
            const int chunk = oc + 8 * j;
            const sh8 vh = *(const sh8*)(eh + npx * 264 + chunk * 8);
            const sh8 vl = *(const sh8*)(el + npx * 264 + chunk * 8);
#pragma unroll
            for (int e = 0; e < 8; ++e) {
                const float f = bf_f((unsigned short)vh[e]) + bf_f((unsigned short)vl[e]);
                s2 = fmaf(f, f, s2);
            }
        }
        s2 += __shfl_xor(s2, 1); s2 += __shfl_xor(s2, 2); s2 += __shfl_xor(s2, 4);
        if (oc == 0) neL[npx] = s2;
    }
    // phase 2 only reads e (read-only); neL consumed after the post-merge barrier

    // ================= Phase 2: distance + fused top-3 (no barriers in loop) =================
    float t3a[4], t3b[4], t3c[4];
#pragma unroll
    for (int i = 0; i < 4; ++i) { t3a[i] = FLT_MAX; t3b[i] = FLT_MAX; t3c[i] = FLT_MAX; }
    __syncthreads();   // e + ne complete

    for (int pair = 0; pair < 8; ++pair) {
        f32x4 acc2[2][4];
#pragma unroll
        for (int i = 0; i < 2; ++i)
#pragma unroll
            for (int j = 0; j < 4; ++j) acc2[i][j] = (f32x4)0.f;

#pragma unroll 2
        for (int ks = 0; ks < 8; ++ks) {
            sh8 cah[2], cal[2], ebh[4], ebl[4];
#pragma unroll
            for (int cp = 0; cp < 2; ++cp) {
                const int chunk = pair * 2 + cp;
                const size_t off = ((size_t)(((chunk * 8 + w8) * 8 + ks) * 64 + l)) * 8;
                cah[cp] = *(const sh8*)(chi + off);
                cal[cp] = *(const sh8*)(clo + off);
            }
#pragma unroll
            for (int nt = 0; nt < 4; ++nt) {
                const int ebo = (nt * 16 + li) * 264 + (ks * 4 + g) * 8;
                ebh[nt] = *(const sh8*)(eh + ebo);
                ebl[nt] = *(const sh8*)(el + ebo);
            }
#pragma unroll
            for (int cp = 0; cp < 2; ++cp)
#pragma unroll
                for (int nt = 0; nt < 4; ++nt) {
                    f32x4 c = acc2[cp][nt];
                    c = MFMA(cah[cp], ebh[nt], c);
                    c = MFMA(cah[cp], ebl[nt], c);
                    c = MFMA(cal[cp], ebh[nt], c);
                    acc2[cp][nt] = c;
                }
        }

        // fold: v = ||c||^2 - 2 e.c  (ne added at the very end; constant per px)
#pragma unroll
        for (int cp = 0; cp < 2; ++cp) {
            const f32x4 nc4 = *(const f32x4*)(ncg + (pair * 2 + cp) * 128 + w8 * 16 + g * 4);
#pragma unroll
            for (int nt = 0; nt < 4; ++nt)
#pragma unroll
                for (int r = 0; r < 4; ++r) {
                    const float v = fmaf(-2.f, acc2[cp][nt][r], nc4[r]);
                    const float m0 = fminf(t3a[nt], v);
                    const float x0 = fmaxf(t3a[nt], v);
                    const float m1 = fminf(t3b[nt], x0);
                    const float x1 = fmaxf(t3b[nt], x0);
                    const float m2 = fminf(t3c[nt], x1);
                    t3a[nt] = m0; t3b[nt] = m1; t3c[nt] = m2;
                }
        }
    }

    // ---- merge across the 4 lanes (g) sharing each pixel ----
#pragma unroll
    for (int m = 16; m < 64; m <<= 1) {
#pragma unroll
        for (int nt = 0; nt < 4; ++nt) {
            const float b0 = __shfl_xor(t3a[nt], m);
            const float b1 = __shfl_xor(t3b[nt], m);
            const float b2 = __shfl_xor(t3c[nt], m);
            const float c0m = fminf(t3a[nt], b0);
            const float c1m = fminf(fmaxf(t3a[nt], b0), fminf(t3b[nt], b1));
            const float c2m = fminf(fminf(fmaxf(t3a[nt], b1), fmaxf(t3b[nt], b0)),
                                    fminf(t3c[nt], b2));
            t3a[nt] = c0m; t3b[nt] = c1m; t3c[nt] = c2m;
        }
    }
    // ---- cross-wave merge via LDS ----
    float* WM = (float*)(sm + LDS_WM);
    if (l < 16) {
#pragma unroll
        for (int nt = 0; nt < 4; ++nt) {
            f32x4 w = {t3a[nt], t3b[nt], t3c[nt], 0.f};
            *(f32x4*)(WM + (w8 * 64 + nt * 16 + l) * 4) = w;
        }
    }
    __syncthreads();

    if (t < 64) {
        float a = FLT_MAX, bb = FLT_MAX, cc = FLT_MAX;
#pragma unroll
        for (int w = 0; w < 8; ++w) {
            const f32x4 m = *(const f32x4*)(WM + (w * 64 + t) * 4);
#pragma unroll
            for (int j = 0; j < 3; ++j) {
                const float v = m[j];
                const float m0 = fminf(a, v), x0 = fmaxf(a, v);
                const float m1 = fminf(bb, x0), x1 = fmaxf(bb, x0);
                const float m2 = fminf(cc, x1);
                a = m0; bb = m1; cc = m2;
            }
        }
        const float nep = neL[t];
        const float d0 = sqrtf(fmaxf(nep + a, 0.f));
        const float d1 = sqrtf(fmaxf(nep + bb, 0.f));
        const float d2 = sqrtf(fmaxf(nep + cc, 0.f));
        const float wsum = 1.f + expf(d0 - d1) + expf(d0 - d2);
        outp[((size_t)b << 12) + (h << 6) + t] = d0 / wsum;
    }
}

extern "C" void kernel_launch(void* const* d_in, const int* in_sizes, int n_in,
                              void* d_out, int out_size, void* d_ws, size_t ws_size,
                              hipStream_t stream) {
    (void)in_sizes; (void)n_in; (void)out_size; (void)ws_size;
    const float* p1    = (const float*)d_in[0];
    const float* p2    = (const float*)d_in[1];
    const float* projw = (const float*)d_in[2];
    const float* projb = (const float*)d_in[3];
    const float* cent  = (const float*)d_in[4];
    float* outp = (float*)d_out;
    char* ws = (char*)d_ws;

    float* ncg = (float*)(ws + WS_NCG);
    unsigned short* whi = (unsigned short*)(ws + WS_WHI);
    unsigned short* wlo = (unsigned short*)(ws + WS_WLO);
    unsigned short* chi = (unsigned short*)(ws + WS_CHI);
    unsigned short* clo = (unsigned short*)(ws + WS_CLO);

    hipLaunchKernelGGL(cnorm_kernel, dim3(P_ / 4), dim3(256), 0, stream, cent, ncg);
    hipLaunchKernelGGL(prep_w, dim3(192), dim3(256), 0, stream, projw, whi, wlo);
    hipLaunchKernelGGL(prep_c, dim3(256), dim3(256), 0, stream, cent, chi, clo);
    hipLaunchKernelGGL(fused2, dim3(B_ * H1_), dim3(512), 0, stream,
                       p1, p2, projb, whi, wlo, chi, clo, ncg, outp);
}